// Round 9
// baseline (363.882 us; speedup 1.0000x reference)
//
#include <hip/hip_runtime.h>
#include <hip/hip_fp16.h>

#define NN 100000      // nodes
#define NE 1600000     // edges
#define INC 128        // in channels
#define HID 96         // hidden
#define NG 512         // graphs

#define GEMM1_BLOCKS 1563        // ceil(NN/64)
#define REORDER_BLOCKS 6250      // ceil(NE/256)

// ---------------- CSR build: histogram, scan ----------------
__global__ void k_zero(int* __restrict__ off, int* __restrict__ cur) {
    int i = blockIdx.x * blockDim.x + threadIdx.x;
    if (i < NN + 1) off[i] = 0;
    if (i < NN) cur[i] = 0;
}

__global__ void k_hist(const int* __restrict__ dst, int* __restrict__ off) {
    int e = blockIdx.x * blockDim.x + threadIdx.x;
    if (e < NE) atomicAdd(&off[dst[e] + 1], 1);
}

// 3-phase scan: blockwise scan (1024 elems/block) -> scan block sums -> add
__global__ __launch_bounds__(256) void k_scan1(int* __restrict__ a, int* __restrict__ bsum, int n) {
    __shared__ int s[256];
    int base = blockIdx.x * 1024 + threadIdx.x * 4;
    int v0 = (base + 0 < n) ? a[base + 0] : 0;
    int v1 = (base + 1 < n) ? a[base + 1] : 0;
    int v2 = (base + 2 < n) ? a[base + 2] : 0;
    int v3 = (base + 3 < n) ? a[base + 3] : 0;
    v1 += v0; v2 += v1; v3 += v2;
    s[threadIdx.x] = v3;
    __syncthreads();
    for (int ofs = 1; ofs < 256; ofs <<= 1) {
        int t = (threadIdx.x >= ofs) ? s[threadIdx.x - ofs] : 0;
        __syncthreads();
        s[threadIdx.x] += t;
        __syncthreads();
    }
    int pre = (threadIdx.x > 0) ? s[threadIdx.x - 1] : 0;
    v0 += pre; v1 += pre; v2 += pre; v3 += pre;
    if (base + 0 < n) a[base + 0] = v0;
    if (base + 1 < n) a[base + 1] = v1;
    if (base + 2 < n) a[base + 2] = v2;
    if (base + 3 < n) a[base + 3] = v3;
    if (threadIdx.x == 255) bsum[blockIdx.x] = s[255];
}

__global__ __launch_bounds__(128) void k_scan2(int* __restrict__ bsum, int nb) {
    __shared__ int s[128];
    int v = (threadIdx.x < nb) ? bsum[threadIdx.x] : 0;
    s[threadIdx.x] = v;
    __syncthreads();
    for (int ofs = 1; ofs < 128; ofs <<= 1) {
        int t = (threadIdx.x >= ofs) ? s[threadIdx.x - ofs] : 0;
        __syncthreads();
        s[threadIdx.x] += t;
        __syncthreads();
    }
    if (threadIdx.x < nb) bsum[threadIdx.x] = s[threadIdx.x];  // inclusive
}

__global__ __launch_bounds__(256) void k_scan3(int* __restrict__ a, const int* __restrict__ bsum, int n) {
    int b = blockIdx.x;
    if (b == 0) return;
    int add = bsum[b - 1];
    int base = b * 1024 + threadIdx.x * 4;
#pragma unroll
    for (int j = 0; j < 4; ++j) {
        int idx = base + j;
        if (idx < n) a[idx] += add;
    }
}

// dis[i] = rsqrt(deg_in + selfloop)
__global__ void k_dis(const int* __restrict__ off, float* __restrict__ dis) {
    int i = blockIdx.x * blockDim.x + threadIdx.x;
    if (i < NN) dis[i] = rsqrtf((float)(off[i + 1] - off[i] + 1));
}

// ---------------- FUSED: gemm1 (compute-bound) ∥ reorder (write-bound) ----------------
__global__ __launch_bounds__(256) void k_gemm1_reorder(
        const float* __restrict__ X, const float* __restrict__ W, __half* __restrict__ Yh,
        const int* __restrict__ src, const int* __restrict__ dst,
        const int* __restrict__ off, int* __restrict__ cur,
        const float* __restrict__ dis, int2* __restrict__ ssrcw) {
    __shared__ float xsT[32][64];   // X tile, transposed
    __shared__ float ws[32 * 96];   // W tile
    const int tid = threadIdx.x;

    if (blockIdx.x >= GEMM1_BLOCKS) {
        // -------- reorder body --------
        int e = (blockIdx.x - GEMM1_BLOCKS) * 256 + tid;
        if (e < NE) {
            int s = src[e], d = dst[e];
            int p = off[d] + atomicAdd(&cur[d], 1);
            float w = dis[s] * dis[d];
            ssrcw[p] = make_int2(s, __float_as_int(w));
        }
        return;
    }

    // -------- gemm body (K = INC = 128) --------
    const int row0 = blockIdx.x * 64;
    const int rg = tid >> 4;        // 0..15
    const int cg = tid & 15;        // 0..15
    const int r0 = rg * 4, c0 = cg * 6;
    float acc[4][6] = {};
    const int srow = tid & 63;      // staging row
    const int sq = tid >> 6;        // 0..3

    for (int k0 = 0; k0 < INC; k0 += 32) {
        {
            int grow = row0 + srow;
            float4 v = make_float4(0.f, 0.f, 0.f, 0.f);
            float4 u = make_float4(0.f, 0.f, 0.f, 0.f);
            if (grow < NN) {
                v = *(const float4*)&X[(size_t)grow * INC + k0 + sq * 4];
                u = *(const float4*)&X[(size_t)grow * INC + k0 + (sq + 4) * 4];
            }
            xsT[sq * 4 + 0][srow] = v.x;
            xsT[sq * 4 + 1][srow] = v.y;
            xsT[sq * 4 + 2][srow] = v.z;
            xsT[sq * 4 + 3][srow] = v.w;
            xsT[(sq + 4) * 4 + 0][srow] = u.x;
            xsT[(sq + 4) * 4 + 1][srow] = u.y;
            xsT[(sq + 4) * 4 + 2][srow] = u.z;
            xsT[(sq + 4) * 4 + 3][srow] = u.w;
        }
        {
            const float4* wsrc = (const float4*)(W + k0 * 96);
            float4* wdst = (float4*)ws;
            wdst[tid] = wsrc[tid];
            wdst[tid + 256] = wsrc[tid + 256];
            wdst[tid + 512] = wsrc[tid + 512];
        }
        __syncthreads();
#pragma unroll
        for (int kk = 0; kk < 32; ++kk) {
            float4 xv = *(const float4*)&xsT[kk][r0];
            float wv[6];
            *(float2*)&wv[0] = *(const float2*)&ws[kk * 96 + c0];
            *(float2*)&wv[2] = *(const float2*)&ws[kk * 96 + c0 + 2];
            *(float2*)&wv[4] = *(const float2*)&ws[kk * 96 + c0 + 4];
            float xr[4] = {xv.x, xv.y, xv.z, xv.w};
#pragma unroll
            for (int i = 0; i < 4; ++i)
#pragma unroll
                for (int j = 0; j < 6; ++j) acc[i][j] += xr[i] * wv[j];
        }
        __syncthreads();
    }
#pragma unroll
    for (int i = 0; i < 4; ++i) {
        int grow = row0 + r0 + i;
        if (grow >= NN) break;
        __half2* yp = (__half2*)&Yh[(size_t)grow * HID + c0];
        yp[0] = __floats2half2_rn(acc[i][0], acc[i][1]);
        yp[1] = __floats2half2_rn(acc[i][2], acc[i][3]);
        yp[2] = __floats2half2_rn(acc[i][4], acc[i][5]);
    }
}

// ---------------- GEMM2: Yh[N,96] = fp16( Xh[N,96](fp16) @ W[96,96](f32) ) ----------------
// 128 rows/block, 256 threads, thread tile 8x6, K-chunks of 32.
__global__ __launch_bounds__(256) void k_gemm2(const __half* __restrict__ Xh,
                                               const float* __restrict__ W,
                                               __half* __restrict__ Yh) {
    __shared__ __half xsT[32][136];   // A tile transposed (pad to kill conflicts)
    __shared__ float ws[32 * 96];     // W chunk
    const int tid = threadIdx.x;
    const int row0 = blockIdx.x * 128;
    const int rg = tid >> 4;          // 0..15
    const int cg = tid & 15;          // 0..15
    const int r0 = rg * 8, c0 = cg * 6;
    float acc[8][6] = {};

    const int sr = tid & 127;         // staging row
    const int sh = tid >> 7;          // 0/1 -> k-half

    for (int k0 = 0; k0 < HID; k0 += 32) {
        // stage A^T fp16: 128 rows x 32 ks
        {
            int grow = row0 + sr;
            uint4 A = make_uint4(0, 0, 0, 0), B = make_uint4(0, 0, 0, 0);
            if (grow < NN) {
                A = *(const uint4*)&Xh[(size_t)grow * HID + k0 + sh * 16];
                B = *(const uint4*)&Xh[(size_t)grow * HID + k0 + sh * 16 + 8];
            }
            const unsigned au[8] = {A.x, A.y, A.z, A.w, B.x, B.y, B.z, B.w};
#pragma unroll
            for (int q = 0; q < 8; ++q) {
                __half2 h2 = *(const __half2*)&au[q];
                xsT[sh * 16 + 2 * q + 0][sr] = h2.x;
                xsT[sh * 16 + 2 * q + 1][sr] = h2.y;
            }
        }
        // stage W chunk (f32, rows contiguous)
        {
            const float4* wsrc = (const float4*)(W + k0 * 96);
            float4* wdst = (float4*)ws;
            wdst[tid] = wsrc[tid];
            wdst[tid + 256] = wsrc[tid + 256];
            wdst[tid + 512] = wsrc[tid + 512];
        }
        __syncthreads();
#pragma unroll
        for (int kk = 0; kk < 32; ++kk) {
            uint4 xv = *(const uint4*)&xsT[kk][r0];   // 8 halfs (r0*2 bytes, 16B aligned)
            const unsigned xu[4] = {xv.x, xv.y, xv.z, xv.w};
            float xr[8];
#pragma unroll
            for (int q = 0; q < 4; ++q) {
                float2 f2 = __half22float2(*(const __half2*)&xu[q]);
                xr[2 * q] = f2.x; xr[2 * q + 1] = f2.y;
            }
            float wv[6];
            *(float2*)&wv[0] = *(const float2*)&ws[kk * 96 + c0];
            *(float2*)&wv[2] = *(const float2*)&ws[kk * 96 + c0 + 2];
            *(float2*)&wv[4] = *(const float2*)&ws[kk * 96 + c0 + 4];
#pragma unroll
            for (int i = 0; i < 8; ++i)
#pragma unroll
                for (int j = 0; j < 6; ++j) acc[i][j] += xr[i] * wv[j];
        }
        __syncthreads();
    }
#pragma unroll
    for (int i = 0; i < 8; ++i) {
        int grow = row0 + r0 + i;
        if (grow >= NN) break;
        __half2* yp = (__half2*)&Yh[(size_t)grow * HID + c0];
        yp[0] = __floats2half2_rn(acc[i][0], acc[i][1]);
        yp[1] = __floats2half2_rn(acc[i][2], acc[i][3]);
        yp[2] = __floats2half2_rn(acc[i][4], acc[i][5]);
    }
}

// ---------------- fused GCN aggregation + node-logit partial ----------------
// 32 threads per destination node; thread t owns features {t, t+32, t+64}.
// PHASE 1: nodeOut[d] = bn + h1 . Wn[0:96]      PHASE 2: nodeOut[d] += h2 . Wn[96:192]
// Output H written as fp16.
template <int PHASE>
__global__ __launch_bounds__(256) void k_agg(const __half* __restrict__ Ah,
                                             const int2* __restrict__ ssrcw,
                                             const int* __restrict__ off,
                                             const float* __restrict__ dis,
                                             const float* __restrict__ bias,
                                             const float* __restrict__ Wn,
                                             const float* __restrict__ bn,
                                             __half* __restrict__ outh,
                                             float* __restrict__ nodeOut) {
    int gid = blockIdx.x * blockDim.x + threadIdx.x;
    int d = gid >> 5;
    int t = gid & 31;
    if (d >= NN) return;
    const int beg = off[d], end = off[d + 1];
    const float dd = dis[d];
    const __half* ad = Ah + (size_t)d * HID;
    float acc0 = __half2float(ad[t]) * dd * dd;
    float acc1 = __half2float(ad[t + 32]) * dd * dd;
    float acc2 = __half2float(ad[t + 64]) * dd * dd;
    int j = beg;
    // 8-wide unroll: batch descriptor loads, then 24 independent gathers
    for (; j + 7 < end; j += 8) {
        int2 e[8];
#pragma unroll
        for (int q = 0; q < 8; ++q) e[q] = ssrcw[j + q];
        float w[8];
        const __half* ap[8];
#pragma unroll
        for (int q = 0; q < 8; ++q) {
            w[q] = __int_as_float(e[q].y);
            ap[q] = Ah + (size_t)e[q].x * HID;
        }
        float g0[8], g1[8], g2[8];
#pragma unroll
        for (int q = 0; q < 8; ++q) {
            g0[q] = __half2float(ap[q][t]);
            g1[q] = __half2float(ap[q][t + 32]);
            g2[q] = __half2float(ap[q][t + 64]);
        }
#pragma unroll
        for (int q = 0; q < 8; ++q) {
            acc0 += g0[q] * w[q];
            acc1 += g1[q] * w[q];
            acc2 += g2[q] * w[q];
        }
    }
    for (; j < end; ++j) {
        int2 e0 = ssrcw[j];
        float w0 = __int_as_float(e0.y);
        const __half* a0 = Ah + (size_t)e0.x * HID;
        acc0 += __half2float(a0[t]) * w0;
        acc1 += __half2float(a0[t + 32]) * w0;
        acc2 += __half2float(a0[t + 64]) * w0;
    }
    float h0 = fmaxf(acc0 + bias[t], 0.f);
    float h1v = fmaxf(acc1 + bias[t + 32], 0.f);
    float h2v = fmaxf(acc2 + bias[t + 64], 0.f);
    __half* o = outh + (size_t)d * HID;
    o[t] = __float2half(h0);
    o[t + 32] = __float2half(h1v);
    o[t + 64] = __float2half(h2v);

    const int woff = (PHASE == 1) ? 0 : 96;
    float partial = h0 * Wn[woff + t] + h1v * Wn[woff + t + 32] + h2v * Wn[woff + t + 64];
#pragma unroll
    for (int m = 16; m; m >>= 1) partial += __shfl_down(partial, m, 32);
    if (t == 0) {
        if (PHASE == 1) nodeOut[d] = partial + bn[0];
        else            nodeOut[d] += partial;
    }
}

// ---------------- graph pooling + graph head (fp16 H inputs) ----------------
// 768 threads: 4 node-ways x 192 features
__global__ __launch_bounds__(768) void k_pool(const __half* __restrict__ h1,
                                              const __half* __restrict__ h2,
                                              const int* __restrict__ batch,
                                              const float* __restrict__ Wg,
                                              const float* __restrict__ bg,
                                              float* __restrict__ out) {
    int g = blockIdx.x;
    int tid = threadIdx.x;       // 0..767
    int way = tid / 192;         // 0..3
    int f = tid - way * 192;     // 0..191

    int lo = 0, hi = NN;
    while (lo < hi) { int mid = (lo + hi) >> 1; if (batch[mid] < g) lo = mid + 1; else hi = mid; }
    int start = lo;
    hi = NN;
    while (lo < hi) { int mid = (lo + hi) >> 1; if (batch[mid] < g + 1) lo = mid + 1; else hi = mid; }
    int end = lo;

    const __half* hsrc = (f < HID) ? h1 : h2;
    int ff = (f < HID) ? f : f - HID;
    float sum = 0.f, mx = 0.f;  // h >= 0 post-relu
    for (int n = start + way; n < end; n += 4) {
        float v = __half2float(hsrc[(size_t)n * HID + ff]);
        sum += v;
        mx = fmaxf(mx, v);
    }
    __shared__ float rsum[4][192];
    __shared__ float rmax[4][192];
    rsum[way][f] = sum;
    rmax[way][f] = mx;
    __syncthreads();
    if (way == 0) {
        sum = rsum[0][f] + rsum[1][f] + rsum[2][f] + rsum[3][f];
        mx = fmaxf(fmaxf(rmax[0][f], rmax[1][f]), fmaxf(rmax[2][f], rmax[3][f]));
        float cnt = (float)(end - start);
        float mean = sum / fmaxf(cnt, 1.0f);
        rsum[0][f] = mean * Wg[f] + mx * Wg[192 + f];
    }
    __syncthreads();
    if (tid < 64) {
        float acc = rsum[0][tid] + rsum[0][tid + 64] + rsum[0][tid + 128];
#pragma unroll
        for (int m = 32; m; m >>= 1) acc += __shfl_down(acc, m, 64);
        if (tid == 0) out[g] = acc + bg[0];
    }
}

extern "C" void kernel_launch(void* const* d_in, const int* in_sizes, int n_in,
                              void* d_out, int out_size, void* d_ws, size_t ws_size,
                              hipStream_t stream) {
    const float* x    = (const float*)d_in[0];
    const int*   ei   = (const int*)d_in[1];
    const int*   srcp = ei;
    const int*   dstp = ei + NE;
    const int*   batch = (const int*)d_in[2];
    const float* W1 = (const float*)d_in[3];
    const float* b1 = (const float*)d_in[4];
    const float* W2 = (const float*)d_in[5];
    const float* b2 = (const float*)d_in[6];
    const float* Wn = (const float*)d_in[7];
    const float* bn = (const float*)d_in[8];
    const float* Wg = (const float*)d_in[9];
    const float* bg = (const float*)d_in[10];
    float* out = (float*)d_out;

    char* p = (char*)d_ws;
    auto alloc = [&](size_t bytes) {
        char* r = p;
        p += (bytes + 255) & ~(size_t)255;
        return (void*)r;
    };
    float*  dis   = (float*)alloc(NN * 4);
    int*    off   = (int*)alloc((NN + 1) * 4);
    int*    cur   = (int*)alloc(NN * 4);
    int*    bsum  = (int*)alloc(128 * 4);
    int2*   ssrcw = (int2*)alloc((size_t)NE * 8);
    __half* Ah    = (__half*)alloc((size_t)NN * HID * 2);   // hw buffer (both convs)
    __half* H1h   = (__half*)alloc((size_t)NN * HID * 2);
    __half* H2h   = (__half*)alloc((size_t)NN * HID * 2);

    const int TPB = 256;
    const int nScan = NN + 1;
    const int nbScan = (nScan + 1023) / 1024;    // 98

    // CSR prelude
    k_zero<<<(NN + TPB) / TPB, TPB, 0, stream>>>(off, cur);
    k_hist<<<(NE + TPB - 1) / TPB, TPB, 0, stream>>>(dstp, off);
    k_scan1<<<nbScan, 256, 0, stream>>>(off, bsum, nScan);
    k_scan2<<<1, 128, 0, stream>>>(bsum, nbScan);
    k_scan3<<<nbScan, 256, 0, stream>>>(off, bsum, nScan);
    k_dis<<<(NN + TPB - 1) / TPB, TPB, 0, stream>>>(off, dis);

    // FUSED: gemm1 (blocks 0..1562)  ∥  reorder (blocks 1563..7812)
    k_gemm1_reorder<<<GEMM1_BLOCKS + REORDER_BLOCKS, 256, 0, stream>>>(
        x, W1, Ah, srcp, dstp, off, cur, dis, ssrcw);

    const int aggThreads = NN * 32;
    float* nodeOut = out + NG;

    // conv1 aggregate: H1h = fp16(relu(agg(Ah) + b1)) ; nodeOut = bn + h1.Wn[:96]
    k_agg<1><<<(aggThreads + TPB - 1) / TPB, TPB, 0, stream>>>(Ah, ssrcw, off, dis, b1, Wn, bn, H1h, nodeOut);

    // conv2: Ah = fp16(H1h@W2) ; H2h = fp16(relu(agg(Ah) + b2)) ; nodeOut += h2.Wn[96:]
    k_gemm2<<<(NN + 127) / 128, 256, 0, stream>>>(H1h, W2, Ah);
    k_agg<2><<<(aggThreads + TPB - 1) / TPB, TPB, 0, stream>>>(Ah, ssrcw, off, dis, b2, Wn, bn, H2h, nodeOut);

    // pooling + graph head
    k_pool<<<NG, 768, 0, stream>>>(H1h, H2h, batch, Wg, bg, out);
}